// Round 5
// baseline (699.528 us; speedup 1.0000x reference)
//
#include <hip/hip_runtime.h>

#define LL 784
#define CHI 128
#define CLS 10
#define BC 16
#define NBLK 64          // 1024/16

typedef __attribute__((ext_vector_type(8))) short short8;
typedef __attribute__((ext_vector_type(4))) float floatx4;

__device__ inline unsigned int f2bf(float v) {
    unsigned int u = __float_as_uint(v);
    u += 0x7fffu + ((u >> 16) & 1u);   // RNE
    return u >> 16;
}

// workgroup barrier that does NOT drain vmcnt — keeps W prefetch in flight.
__device__ inline void lds_barrier() {
    asm volatile("s_waitcnt lgkmcnt(0)\n\ts_barrier" ::: "memory");
}

// value from lane^1 (quad_perm [1,0,3,2]) — VALU DPP, no LDS pipe use.
__device__ inline float dpp_xor1(float v) {
    int r = __builtin_amdgcn_update_dpp(0, __float_as_int(v), 0xB1, 0xF, 0xF, true);
    return __int_as_float(r);
}

// ---------------------------------------------------------------------------
// prep: W fp32 (L,2,CHI,CHI) -> bf16 MFMA B-fragments via LDS transpose.
// ws uint4 index: (((n*8 + nt)*2 + s)*4 + kt)*64 + l
//   lane l elem j: value = W[n][s][a = kt*32 + (l>>4)*8 + j][c = nt*16 + (l&15)]
// ---------------------------------------------------------------------------
__global__ __launch_bounds__(256) void prep_kernel(const float* __restrict__ W,
                                                   uint4* __restrict__ ws4) {
    __shared__ float tile[32 * 132];
    const int b = blockIdx.x;            // n*8 + s*4 + kt
    const int n = b >> 3, s = (b >> 2) & 1, kt = b & 3;
    const float* Wp = W + ((size_t)(n * 2 + s) * CHI + kt * 32) * CHI;
    const int t = threadIdx.x;
    #pragma unroll
    for (int k = 0; k < 4; k++) {
        int v = t + k * 256;             // 0..1023 float4s
        int a = v >> 5, c4 = v & 31;
        float4 val = *(const float4*)(Wp + a * CHI + c4 * 4);
        *(float4*)&tile[a * 132 + c4 * 4] = val;
    }
    __syncthreads();
    const int l = t & 63, f0 = t >> 6;
    const int m_ = l & 15, q_ = l >> 4;
    #pragma unroll
    for (int ff = 0; ff < 2; ff++) {
        int nt = f0 + ff * 4;
        const float* tp = &tile[(q_ * 8) * 132 + nt * 16 + m_];
        uint4 pk;
        pk.x = f2bf(tp[0 * 132]) | (f2bf(tp[1 * 132]) << 16);
        pk.y = f2bf(tp[2 * 132]) | (f2bf(tp[3 * 132]) << 16);
        pk.z = f2bf(tp[4 * 132]) | (f2bf(tp[5 * 132]) << 16);
        pk.w = f2bf(tp[6 * 132]) | (f2bf(tp[7 * 132]) << 16);
        ws4[(size_t)(((n * 8 + nt) * 2 + s) * 4 + kt) * 64 + l] = pk;
    }
}

// ---------------------------------------------------------------------------
// main: 64 blocks x 512 threads (8 waves). Block owns 16 batch rows.
// h (fp32, exact) lives in wave registers (C-layout). bf16 h in LDS in
// A-fragment layout, ping-pong buffered -> ONE lgkmcnt-only barrier/site.
// W frags: 4-deep register prefetch (bA..bD), refill site n+4 after MFMAs.
// __launch_bounds__(512, 2): 256 VGPR/wave so the 4x32-VGPR W pipeline
// actually stays in registers (round-4 failure: default bounds capped at
// 60 VGPRs and the compiler collapsed the prefetch).
// ---------------------------------------------------------------------------
__global__ __launch_bounds__(512, 2) void mps_kernel(const float* __restrict__ x,
                                                  const unsigned short* __restrict__ ws,
                                                  const float* __restrict__ V,
                                                  float* __restrict__ out) {
    __shared__ short8 afbuf[2][256];     // [par][kt*64 + l], 2 x 4 KB
    __shared__ float xs[2][8][32];       // [par][site&7][s*16 + row]
    __shared__ float hfin[16 * 132];     // final h for h@V

    const int t = threadIdx.x;
    const int w = t >> 6, l = t & 63;
    const int m = l & 15, q = l >> 4;
    const int rb = blockIdx.x * BC;

    // init afbuf[0] = bf16(1.0)  (1024 uints, 512 threads -> 2 each)
    for (int i = t; i < 1024; i += 512)
        ((unsigned int*)&afbuf[0][0])[i] = 0x3F803F80u;

    // ---- x staging: chunks 0,1 to LDS; chunk 2 in registers ----
    const float* xrowp = x + (size_t)(rb + m) * (2 * LL) + (size_t)(q & 1) * LL;
    float4 xc2a, xc2b;
    if (l < 32) {
        float4 a0 = *(const float4*)(xrowp + 0);
        float4 b0 = *(const float4*)(xrowp + 4);
        float4 a1 = *(const float4*)(xrowp + 8);
        float4 b1 = *(const float4*)(xrowp + 12);
        float v0[8] = {a0.x, a0.y, a0.z, a0.w, b0.x, b0.y, b0.z, b0.w};
        float v1[8] = {a1.x, a1.y, a1.z, a1.w, b1.x, b1.y, b1.z, b1.w};
        #pragma unroll
        for (int k = 0; k < 8; k++) xs[0][k][(q & 1) * 16 + m] = v0[k];
        #pragma unroll
        for (int k = 0; k < 8; k++) xs[1][k][(q & 1) * 16 + m] = v1[k];
        xc2a = *(const float4*)(xrowp + 16);
        xc2b = *(const float4*)(xrowp + 20);
    }

    // ---- W prefetch: 4 register buffers of 8 frags (f = s*4 + kt) ----
    const unsigned short* wsw = ws + (size_t)w * 4096 + (size_t)l * 8;
    short8 bA[8], bB[8], bC[8], bD[8];
    #pragma unroll
    for (int f = 0; f < 8; f++) {
        bA[f] = *(const short8*)(wsw + (size_t)0 * 32768 + f * 512);
        bB[f] = *(const short8*)(wsw + (size_t)1 * 32768 + f * 512);
        bC[f] = *(const short8*)(wsw + (size_t)2 * 32768 + f * 512);
        bD[f] = *(const short8*)(wsw + (size_t)3 * 32768 + f * 512);
    }

    floatx4 hacc = (floatx4){1.f, 1.f, 1.f, 1.f};
    const int kt_w = w >> 1;
    const int qp_w = (w & 1) * 2 + (m >> 3);
    const int col2 = (m & 7) >> 1;

    __syncthreads();

#define SITE_BODY(NN, BUF) do {                                                   \
    const int n_ = (NN);                                                          \
    lds_barrier();                                                                \
    if ((n_ & 7) == 0 && n_ >= 8 && n_ + 8 < LL && l < 32) {                      \
        int par_ = ((n_ >> 3) + 1) & 1;                                           \
        float xv_[8] = {xc2a.x, xc2a.y, xc2a.z, xc2a.w,                           \
                        xc2b.x, xc2b.y, xc2b.z, xc2b.w};                          \
        _Pragma("unroll")                                                         \
        for (int k = 0; k < 8; k++) xs[par_][k][(q & 1) * 16 + m] = xv_[k];       \
        if (n_ + 16 < LL) {                                                       \
            xc2a = *(const float4*)(xrowp + n_ + 16);                             \
            xc2b = *(const float4*)(xrowp + n_ + 20);                             \
        }                                                                         \
    }                                                                             \
    short8 af0 = afbuf[n_ & 1][0 * 64 + l];                                       \
    short8 af1 = afbuf[n_ & 1][1 * 64 + l];                                       \
    short8 af2 = afbuf[n_ & 1][2 * 64 + l];                                       \
    short8 af3 = afbuf[n_ & 1][3 * 64 + l];                                       \
    floatx4 x0v = *(const floatx4*)&xs[(n_ >> 3) & 1][n_ & 7][q * 4];             \
    floatx4 x1v = *(const floatx4*)&xs[(n_ >> 3) & 1][n_ & 7][16 + q * 4];        \
    floatx4 z = (floatx4){0.f, 0.f, 0.f, 0.f};                                    \
    floatx4 a00 = __builtin_amdgcn_mfma_f32_16x16x32_bf16(af0, BUF[0], z, 0, 0, 0); \
    floatx4 a01 = __builtin_amdgcn_mfma_f32_16x16x32_bf16(af2, BUF[2], z, 0, 0, 0); \
    floatx4 a10 = __builtin_amdgcn_mfma_f32_16x16x32_bf16(af0, BUF[4], z, 0, 0, 0); \
    floatx4 a11 = __builtin_amdgcn_mfma_f32_16x16x32_bf16(af2, BUF[6], z, 0, 0, 0); \
    a00 = __builtin_amdgcn_mfma_f32_16x16x32_bf16(af1, BUF[1], a00, 0, 0, 0);     \
    a01 = __builtin_amdgcn_mfma_f32_16x16x32_bf16(af3, BUF[3], a01, 0, 0, 0);     \
    a10 = __builtin_amdgcn_mfma_f32_16x16x32_bf16(af1, BUF[5], a10, 0, 0, 0);     \
    a11 = __builtin_amdgcn_mfma_f32_16x16x32_bf16(af3, BUF[7], a11, 0, 0, 0);     \
    if (n_ + 4 < LL) {                                                            \
        _Pragma("unroll")                                                         \
        for (int f = 0; f < 8; f++)                                               \
            BUF[f] = *(const short8*)(wsw + (size_t)(n_ + 4) * 32768 + f * 512);  \
    }                                                                             \
    _Pragma("unroll")                                                             \
    for (int i = 0; i < 4; i++)                                                   \
        hacc[i] += x0v[i] * (a00[i] + a01[i]) + x1v[i] * (a10[i] + a11[i]);       \
    float pt0 = dpp_xor1(hacc[0]), pt1 = dpp_xor1(hacc[1]);                       \
    float pt2 = dpp_xor1(hacc[2]), pt3 = dpp_xor1(hacc[3]);                       \
    if (!(m & 1)) {                                                               \
        unsigned int* dst = (unsigned int*)&afbuf[(n_ + 1) & 1][0];               \
        int base_ = (kt_w * 64 + qp_w * 16 + q * 4) * 4 + col2;                   \
        dst[base_ + 0 * 4] = f2bf(hacc[0]) | (f2bf(pt0) << 16);                   \
        dst[base_ + 1 * 4] = f2bf(hacc[1]) | (f2bf(pt1) << 16);                   \
        dst[base_ + 2 * 4] = f2bf(hacc[2]) | (f2bf(pt2) << 16);                   \
        dst[base_ + 3 * 4] = f2bf(hacc[3]) | (f2bf(pt3) << 16);                   \
    }                                                                             \
} while (0)

    for (int n = 0; n < LL; n += 4) {
        SITE_BODY(n, bA);
        SITE_BODY(n + 1, bB);
        SITE_BODY(n + 2, bC);
        SITE_BODY(n + 3, bD);
    }
#undef SITE_BODY

    __syncthreads();

    // hacc (exact fp32) -> LDS, then logits = h @ V
    #pragma unroll
    for (int i = 0; i < 4; i++)
        hfin[(q * 4 + i) * 132 + w * 16 + m] = hacc[i];
    __syncthreads();

    if (t < BC * CLS) {
        int r = t / CLS, cls = t % CLS;
        float sum = 0.f;
        for (int a = 0; a < CHI; a++) sum += hfin[r * 132 + a] * V[a * CLS + cls];
        out[(size_t)(rb + r) * CLS + cls] = sum;
    }
}

extern "C" void kernel_launch(void* const* d_in, const int* in_sizes, int n_in,
                              void* d_out, int out_size, void* d_ws, size_t ws_size,
                              hipStream_t stream) {
    const float* x = (const float*)d_in[0];
    const float* W = (const float*)d_in[1];
    const float* V = (const float*)d_in[2];
    float* out = (float*)d_out;

    prep_kernel<<<LL * 8, 256, 0, stream>>>(W, (uint4*)d_ws);
    mps_kernel<<<NBLK, 512, 0, stream>>>(x, (const unsigned short*)d_ws, V, out);
}